// Round 1
// baseline (3717.828 us; speedup 1.0000x reference)
//
#include <hip/hip_runtime.h>

typedef _Float16 h8 __attribute__((ext_vector_type(8)));
typedef _Float16 h2 __attribute__((ext_vector_type(2)));
typedef float v4f __attribute__((ext_vector_type(4)));

#define B_  256
#define T_  512
#define I_  64
#define H_  512
#define G4_ 2048   // 4*H

// workspace layout (bytes)
#define OFF_W16   0                                   // [2048][512] f16
#define OFF_WIH   (OFF_W16 + 2048*512*2)              // [2048][64]  f16
#define OFF_BIAS  (OFF_WIH + 2048*64*2)               // [2048]      f32 (b_ih+b_hh)
#define OFF_X16   (OFF_BIAS + 2048*4)                 // [512][256][64] f16 (transposed)
#define OFF_H0    (OFF_X16 + 512*256*64*2)            // [256][512] f16
#define OFF_H1    (OFF_H0 + 256*512*2)                // [256][512] f16
#define OFF_CTR   (OFF_H1 + 256*512*2)                // 8 counters, 64B apart

__device__ __forceinline__ float sigf(float x) {
    float e = __builtin_amdgcn_exp2f(-1.442695041f * x);
    return __builtin_amdgcn_rcpf(1.f + e);
}
__device__ __forceinline__ float tanhf_(float x) {
    float e = __builtin_amdgcn_exp2f(2.885390082f * x);  // exp(2x)
    return 1.f - 2.f * __builtin_amdgcn_rcpf(e + 1.f);
}

__global__ void prep_w(const float* __restrict__ Wih, const float* __restrict__ Whh,
                       const float* __restrict__ bih, const float* __restrict__ bhh,
                       _Float16* __restrict__ W16, _Float16* __restrict__ Wih16,
                       float* __restrict__ bias, _Float16* __restrict__ h0,
                       unsigned* __restrict__ ctr) {
    int idx = blockIdx.x * 256 + threadIdx.x;          // grid covers 2048*512
    W16[idx] = (_Float16)Whh[idx];
    if (idx < 2048 * 64)  Wih16[idx] = (_Float16)Wih[idx];
    if (idx < 2048)       bias[idx] = bih[idx] + bhh[idx];
    if (idx < 256 * 512)  h0[idx] = (_Float16)0.f;
    if (idx < 128)        ctr[idx] = 0u;
}

__global__ void prep_x(const float* __restrict__ x, _Float16* __restrict__ x16) {
    int idx = blockIdx.x * 256 + threadIdx.x;          // grid covers 512*256*64
    int t = idx >> 14;                                  // / (256*64)
    int rem = idx & 16383;
    int b = rem >> 6;
    int i = rem & 63;
    x16[idx] = (_Float16)x[((size_t)b * T_ + t) * I_ + i];
}

__launch_bounds__(256, 1)
__global__ void lstm_k(const _Float16* __restrict__ W16, const _Float16* __restrict__ Wih16,
                       const float* __restrict__ bias, const _Float16* __restrict__ x16,
                       _Float16* __restrict__ h0, _Float16* __restrict__ h1,
                       unsigned* __restrict__ ctr) {
    // LDS: A operand chunk-major [kchunk][row][40], padded for bank spread; S = gate staging
    __shared__ _Float16 Als[18][33][40];   // 47520 B
    __shared__ float    S[32][68];         // 8704  B

    const int tid  = threadIdx.x;
    const int lane = tid & 63;
    const int wave = tid >> 6;
    const int bg = blockIdx.x & 7;    // batch group (XCD-friendly under %8 round robin)
    const int cg = blockIdx.x >> 3;   // column group 0..31
    const int B0 = bg * 32;
    const int J0 = cg * 16;
    const int m  = wave & 1;          // m-tile (batch 16-row half)
    const int gp = (wave >> 1) * 2;   // this wave handles gates gp, gp+1
    const int r  = lane & 15;
    const int q  = lane >> 4;

    // --- hoist weight B-fragments into registers (persist across all 512 steps) ---
    h8 bfrag[2][18];
#pragma unroll
    for (int g2 = 0; g2 < 2; ++g2) {
        const int wrow = (gp + g2) * H_ + J0 + r;      // W row = gate column index
#pragma unroll
        for (int kk = 0; kk < 16; ++kk)
            bfrag[g2][kk] = *(const h8*)(W16 + (size_t)wrow * H_ + kk * 32 + q * 8);
#pragma unroll
        for (int kk = 16; kk < 18; ++kk)
            bfrag[g2][kk] = *(const h8*)(Wih16 + (size_t)wrow * I_ + (kk - 16) * 32 + q * 8);
    }
    float biasv[2];
    biasv[0] = bias[gp * H_ + J0 + r];
    biasv[1] = bias[(gp + 1) * H_ + J0 + r];

    // cell state lives in registers of the elementwise-phase owner thread
    float c0 = 0.f, c1 = 0.f;
    const int er = tid >> 3;          // elementwise row 0..31
    const int ej = (tid & 7) * 2;     // elementwise col pair 0,2,..,14

    unsigned* myctr = ctr + bg * 16;  // 64B-separated per-group counters

    for (int s = 0; s < T_; ++s) {
        const _Float16* hp = (s & 1) ? h1 : h0;
        _Float16*       hn = (s & 1) ? h0 : h1;

        // ---- phase A: stage h[32x512] + x_t[32x64] into LDS (f16) ----
        {
            h8 v[8];
#pragma unroll
            for (int it = 0; it < 8; ++it) {
                int row = it * 4 + wave;
                v[it] = *(const h8*)(hp + (size_t)(B0 + row) * H_ + lane * 8);
            }
#pragma unroll
            for (int it = 0; it < 8; ++it) {
                int row = it * 4 + wave;
                *(h8*)&Als[lane >> 2][row][(lane & 3) * 8] = v[it];
            }
            int xrow = tid >> 3, s8 = tid & 7;
            h8 xv = *(const h8*)(x16 + ((size_t)s * B_ + B0 + xrow) * I_ + s8 * 8);
            *(h8*)&Als[16 + (s8 >> 2)][xrow][(s8 & 3) * 8] = xv;
        }
        __syncthreads();

        // ---- phase B: MFMA, K = 512(h) + 64(x) = 18 chunks of 32 ----
        v4f aE0 = {0,0,0,0}, aO0 = {0,0,0,0}, aE1 = {0,0,0,0}, aO1 = {0,0,0,0};
#pragma unroll
        for (int kk = 0; kk < 18; kk += 2) {
            h8 a0 = *(const h8*)&Als[kk][m * 16 + r][q * 8];
            aE0 = __builtin_amdgcn_mfma_f32_16x16x32_f16(a0, bfrag[0][kk], aE0, 0, 0, 0);
            aE1 = __builtin_amdgcn_mfma_f32_16x16x32_f16(a0, bfrag[1][kk], aE1, 0, 0, 0);
            h8 a1 = *(const h8*)&Als[kk + 1][m * 16 + r][q * 8];
            aO0 = __builtin_amdgcn_mfma_f32_16x16x32_f16(a1, bfrag[0][kk + 1], aO0, 0, 0, 0);
            aO1 = __builtin_amdgcn_mfma_f32_16x16x32_f16(a1, bfrag[1][kk + 1], aO1, 0, 0, 0);
        }
        v4f acc0 = aE0 + aO0; acc0 += biasv[0];
        v4f acc1 = aE1 + aO1; acc1 += biasv[1];
        // C/D layout: col = lane&15, row = (lane>>4)*4 + reg  [m89-verified]
#pragma unroll
        for (int reg = 0; reg < 4; ++reg) {
            S[m * 16 + q * 4 + reg][gp * 16 + r]       = acc0[reg];
            S[m * 16 + q * 4 + reg][(gp + 1) * 16 + r] = acc1[reg];
        }
        __syncthreads();

        // ---- phase C: LSTM cell elementwise; thread owns (er, ej), (er, ej+1) ----
        {
            float i0 = sigf  (S[er][ej]);
            float f0 = sigf  (S[er][16 + ej]);
            float g0 = tanhf_(S[er][32 + ej]);
            float o0 = sigf  (S[er][48 + ej]);
            c0 = f0 * c0 + i0 * g0;
            float hv0 = o0 * tanhf_(c0);

            float i1 = sigf  (S[er][ej + 1]);
            float f1 = sigf  (S[er][17 + ej]);
            float g1 = tanhf_(S[er][33 + ej]);
            float o1 = sigf  (S[er][49 + ej]);
            c1 = f1 * c1 + i1 * g1;
            float hv1 = o1 * tanhf_(c1);

            h2 out2; out2[0] = (_Float16)hv0; out2[1] = (_Float16)hv1;
            *(h2*)(hn + (size_t)(B0 + er) * H_ + J0 + ej) = out2;
        }
        __syncthreads();   // order all lanes' h stores before tid0's release

        // ---- per-group barrier: monotonic counter, release/acquire, agent scope ----
        if (tid == 0) {
            __hip_atomic_fetch_add(myctr, 1u, __ATOMIC_RELEASE, __HIP_MEMORY_SCOPE_AGENT);
            const unsigned target = 32u * (unsigned)(s + 1);
            int guard = 0;
            while (__hip_atomic_load(myctr, __ATOMIC_RELAXED, __HIP_MEMORY_SCOPE_AGENT) < target) {
                __builtin_amdgcn_s_sleep(1);
                if (++guard > (1 << 16)) break;   // anti-hang: fail loud, not silent
            }
            (void)__hip_atomic_load(myctr, __ATOMIC_ACQUIRE, __HIP_MEMORY_SCOPE_AGENT);
        }
        __syncthreads();
    }
}

__global__ void fc_k(const _Float16* __restrict__ hlast, const float* __restrict__ Wfc,
                     const float* __restrict__ bfc, float* __restrict__ out) {
    int b = blockIdx.x;
    int lane = threadIdx.x;   // 64 threads
    h8 hv = *(const h8*)(hlast + (size_t)b * H_ + lane * 8);
    float sum = 0.f;
#pragma unroll
    for (int j = 0; j < 8; ++j) sum += (float)hv[j] * Wfc[lane * 8 + j];
    for (int off = 32; off; off >>= 1) sum += __shfl_down(sum, off);
    if (lane == 0) out[b] = sum + bfc[0];
}

extern "C" void kernel_launch(void* const* d_in, const int* in_sizes, int n_in,
                              void* d_out, int out_size, void* d_ws, size_t ws_size,
                              hipStream_t stream) {
    (void)in_sizes; (void)n_in; (void)out_size; (void)ws_size;
    const float* x   = (const float*)d_in[0];
    const float* Wih = (const float*)d_in[1];
    const float* Whh = (const float*)d_in[2];
    const float* bih = (const float*)d_in[3];
    const float* bhh = (const float*)d_in[4];
    const float* Wfc = (const float*)d_in[5];
    const float* bfc = (const float*)d_in[6];
    float* out = (float*)d_out;

    char* ws = (char*)d_ws;
    _Float16* W16   = (_Float16*)(ws + OFF_W16);
    _Float16* Wih16 = (_Float16*)(ws + OFF_WIH);
    float*    biasf = (float*)(ws + OFF_BIAS);
    _Float16* x16   = (_Float16*)(ws + OFF_X16);
    _Float16* h0b   = (_Float16*)(ws + OFF_H0);
    _Float16* h1b   = (_Float16*)(ws + OFF_H1);
    unsigned* ctrb  = (unsigned*)(ws + OFF_CTR);

    hipLaunchKernelGGL(prep_w, dim3((2048 * 512) / 256), dim3(256), 0, stream,
                       Wih, Whh, bih, bhh, W16, Wih16, biasf, h0b, ctrb);
    hipLaunchKernelGGL(prep_x, dim3((512 * 256 * 64) / 256), dim3(256), 0, stream, x, x16);
    hipLaunchKernelGGL(lstm_k, dim3(256), dim3(256), 0, stream,
                       W16, Wih16, biasf, x16, h0b, h1b, ctrb);
    // T=512 even: last write went to buffer 0
    hipLaunchKernelGGL(fc_k, dim3(256), dim3(64), 0, stream, h0b, Wfc, bfc, out);
}

// Round 2
// 1502.853 us; speedup vs baseline: 2.4738x; 2.4738x over previous
//
#include <hip/hip_runtime.h>

typedef _Float16 h8 __attribute__((ext_vector_type(8)));
typedef float v4f __attribute__((ext_vector_type(4)));

#define B_  256
#define T_  512
#define I_  64
#define H_  512

// workspace layout (bytes)
#define OFF_W16   0                                   // [2048][512] f16
#define OFF_WIH   (OFF_W16 + 2048*512*2)              // [2048][64]  f16
#define OFF_BIAS  (OFF_WIH + 2048*64*2)               // [2048]      f32 (b_ih+b_hh)
#define OFF_X16   (OFF_BIAS + 2048*4)                 // [512][256][64] f16 (transposed)
#define OFF_H0    (OFF_X16 + 512*256*64*2)            // [256][512] f16
#define OFF_H1    (OFF_H0 + 256*512*2)                // [256][512] f16
#define OFF_CTR   (OFF_H1 + 256*512*2)                // 8 counters, 64B apart

__device__ __forceinline__ float sigf(float x) {
    float e = __builtin_amdgcn_exp2f(-1.442695041f * x);
    return __builtin_amdgcn_rcpf(1.f + e);
}
__device__ __forceinline__ float tanhf_(float x) {
    float e = __builtin_amdgcn_exp2f(2.885390082f * x);  // exp(2x)
    return 1.f - 2.f * __builtin_amdgcn_rcpf(e + 1.f);
}

union Pack4 { _Float16 f[4]; unsigned long long u; };

__global__ void prep_w(const float* __restrict__ Wih, const float* __restrict__ Whh,
                       const float* __restrict__ bih, const float* __restrict__ bhh,
                       _Float16* __restrict__ W16, _Float16* __restrict__ Wih16,
                       float* __restrict__ bias, _Float16* __restrict__ h0,
                       unsigned* __restrict__ ctr) {
    int idx = blockIdx.x * 256 + threadIdx.x;          // grid covers 2048*512
    W16[idx] = (_Float16)Whh[idx];
    if (idx < 2048 * 64)  Wih16[idx] = (_Float16)Wih[idx];
    if (idx < 2048)       bias[idx] = bih[idx] + bhh[idx];
    // h0 zeros must be visible at the IF$ coherence point (lstm_k reads them
    // with device-scope loads that bypass L2) -> device-scope atomic stores.
    if (idx < 32768)
        __hip_atomic_store((unsigned long long*)h0 + idx, 0ull,
                           __ATOMIC_RELAXED, __HIP_MEMORY_SCOPE_AGENT);
    if (idx < 128)
        __hip_atomic_store(ctr + idx, 0u, __ATOMIC_RELAXED, __HIP_MEMORY_SCOPE_AGENT);
}

__global__ void prep_x(const float* __restrict__ x, _Float16* __restrict__ x16) {
    int idx = blockIdx.x * 256 + threadIdx.x;          // grid covers 512*256*64
    int t = idx >> 14;                                  // / (256*64)
    int rem = idx & 16383;
    int b = rem >> 6;
    int i = rem & 63;
    x16[idx] = (_Float16)x[((size_t)b * T_ + t) * I_ + i];
}

// 128 wgs: 8 batch-groups x 16 col-groups. wg owns 32 batch rows x 32 h-cols
// (=128 gate-cols). Wave w handles gate g=w (both 16-col tiles, both m halves)
// -> B-fragments unique per wave (no duplication): 2 tiles x 18 chunks x h8.
__launch_bounds__(256, 1)
__global__ void lstm_k(const _Float16* __restrict__ W16, const _Float16* __restrict__ Wih16,
                       const float* __restrict__ bias, const _Float16* __restrict__ x16,
                       _Float16* __restrict__ h0, _Float16* __restrict__ h1,
                       unsigned* __restrict__ ctr) {
    __shared__ _Float16 Als[18][33][40];   // 47520 B, A operand chunk-major
    __shared__ float    S[32][132];        // 16896 B, gate staging (+pad)

    const int tid  = threadIdx.x;
    const int lane = tid & 63;
    const int wave = tid >> 6;        // == gate g (0..3)
    const int bg = blockIdx.x & 7;    // batch group
    const int cg = blockIdx.x >> 3;   // column group 0..15
    const int B0 = bg * 32;
    const int J0 = cg * 32;           // h-column base
    const int r  = lane & 15;
    const int q  = lane >> 4;

    // --- hoist weight B-fragments (persist across all 512 steps) ---
    h8 bfrag[2][18];
    float biasv[2];
#pragma unroll
    for (int t = 0; t < 2; ++t) {
        const int wrow = wave * H_ + J0 + t * 16 + r;   // gate-col index
#pragma unroll
        for (int kk = 0; kk < 16; ++kk)
            bfrag[t][kk] = *(const h8*)(W16 + (size_t)wrow * H_ + kk * 32 + q * 8);
#pragma unroll
        for (int kk = 16; kk < 18; ++kk)
            bfrag[t][kk] = *(const h8*)(Wih16 + (size_t)wrow * I_ + (kk - 16) * 32 + q * 8);
        biasv[t] = bias[wrow];
    }

    // phase-C ownership: thread -> (row er, cols ec..ec+3); c stays in VGPRs
    const int er = tid >> 3;
    const int ec = (tid & 7) * 4;
    float c[4] = {0.f, 0.f, 0.f, 0.f};

    unsigned* myctr = ctr + bg * 16;  // 64B-separated per-group counters

    // x prefetch for step 0
    const int xrow = tid >> 3, xs8 = tid & 7;
    h8 xv = *(const h8*)(x16 + ((size_t)B0 + xrow) * I_ + xs8 * 8);

    for (int s = 0; s < T_; ++s) {
        const _Float16* hp = (s & 1) ? h1 : h0;
        _Float16*       hn = (s & 1) ? h0 : h1;

        // ---- phase A: h (device-scope, bypasses L1/L2) + x into LDS ----
        {
            const unsigned long long* hp64 =
                (const unsigned long long*)(hp + (size_t)B0 * H_);
            unsigned long long hv[16];
#pragma unroll
            for (int it = 0; it < 16; ++it)
                hv[it] = __hip_atomic_load(hp64 + tid + 256 * it,
                                           __ATOMIC_RELAXED, __HIP_MEMORY_SCOPE_AGENT);
            *(h8*)&Als[16 + (xs8 >> 2)][xrow][(xs8 & 3) * 8] = xv;
#pragma unroll
            for (int it = 0; it < 16; ++it) {
                int n = tid + 256 * it;    // 8B unit: row n>>7, chunk (n&127)>>3, off (n&7)*4
                *(unsigned long long*)&Als[(n & 127) >> 3][n >> 7][(n & 7) * 4] = hv[it];
            }
        }
        __syncthreads();

        // ---- phase B: MFMA, K = 18 chunks of 32; 4 acc chains/wave ----
        v4f a00 = {0,0,0,0}, a01 = {0,0,0,0}, a10 = {0,0,0,0}, a11 = {0,0,0,0};
#pragma unroll
        for (int kk = 0; kk < 18; ++kk) {
            h8 am0 = *(const h8*)&Als[kk][r][q * 8];
            h8 am1 = *(const h8*)&Als[kk][16 + r][q * 8];
            a00 = __builtin_amdgcn_mfma_f32_16x16x32_f16(am0, bfrag[0][kk], a00, 0, 0, 0);
            a01 = __builtin_amdgcn_mfma_f32_16x16x32_f16(am1, bfrag[0][kk], a01, 0, 0, 0);
            a10 = __builtin_amdgcn_mfma_f32_16x16x32_f16(am0, bfrag[1][kk], a10, 0, 0, 0);
            a11 = __builtin_amdgcn_mfma_f32_16x16x32_f16(am1, bfrag[1][kk], a11, 0, 0, 0);
        }
        // C/D: col = lane&15 (gate-col), row = q*4+reg (batch)  [m89-verified]
#pragma unroll
        for (int reg = 0; reg < 4; ++reg) {
            S[q * 4 + reg][wave * 32 + r]           = a00[reg] + biasv[0];
            S[16 + q * 4 + reg][wave * 32 + r]      = a01[reg] + biasv[0];
            S[q * 4 + reg][wave * 32 + 16 + r]      = a10[reg] + biasv[1];
            S[16 + q * 4 + reg][wave * 32 + 16 + r] = a11[reg] + biasv[1];
        }
        __syncthreads();

        // ---- phase C: LSTM cell; thread owns (er, ec..ec+3) ----
        {
            Pack4 pk;
#pragma unroll
            for (int j = 0; j < 3 + 1; ++j) {
                float iv = sigf  (S[er][ec + j]);
                float fv = sigf  (S[er][32 + ec + j]);
                float gv = tanhf_(S[er][64 + ec + j]);
                float ov = sigf  (S[er][96 + ec + j]);
                c[j] = fv * c[j] + iv * gv;
                pk.f[j] = (_Float16)(ov * tanhf_(c[j]));
            }
            __hip_atomic_store(
                (unsigned long long*)(hn + ((size_t)B0 + er) * H_ + J0 + ec),
                pk.u, __ATOMIC_RELAXED, __HIP_MEMORY_SCOPE_AGENT);
        }
        __syncthreads();   // implicit vmcnt(0): all lanes' h stores ack'd at IF$

        // ---- per-group barrier: relaxed device-scope counter, no L2 flush ----
        if (tid == 0)
            __hip_atomic_fetch_add(myctr, 1u, __ATOMIC_RELAXED, __HIP_MEMORY_SCOPE_AGENT);
        // x prefetch for s+1 overlaps the poll
        if (s + 1 < T_)
            xv = *(const h8*)(x16 + (((size_t)(s + 1)) * B_ + B0 + xrow) * I_ + xs8 * 8);
        if (tid == 0) {
            const unsigned target = 16u * (unsigned)(s + 1);
            int guard = 0;
            while (__hip_atomic_load(myctr, __ATOMIC_RELAXED, __HIP_MEMORY_SCOPE_AGENT) < target) {
                __builtin_amdgcn_s_sleep(1);
                if (++guard > (1 << 17)) break;   // anti-hang: fail loud, not silent
            }
        }
        __syncthreads();
    }
}

__global__ void fc_k(const _Float16* __restrict__ hlast, const float* __restrict__ Wfc,
                     const float* __restrict__ bfc, float* __restrict__ out) {
    int b = blockIdx.x;
    int lane = threadIdx.x;   // 64 threads
    // h was written with device-scope stores (bypassing L2) -> read device-scope
    const unsigned long long* hp64 = (const unsigned long long*)(hlast + (size_t)b * H_);
    Pack4 p0, p1;
    p0.u = __hip_atomic_load(hp64 + lane * 2,     __ATOMIC_RELAXED, __HIP_MEMORY_SCOPE_AGENT);
    p1.u = __hip_atomic_load(hp64 + lane * 2 + 1, __ATOMIC_RELAXED, __HIP_MEMORY_SCOPE_AGENT);
    float sum = 0.f;
#pragma unroll
    for (int j = 0; j < 4; ++j) sum += (float)p0.f[j] * Wfc[lane * 8 + j];
#pragma unroll
    for (int j = 0; j < 4; ++j) sum += (float)p1.f[j] * Wfc[lane * 8 + 4 + j];
    for (int off = 32; off; off >>= 1) sum += __shfl_down(sum, off);
    if (lane == 0) out[b] = sum + bfc[0];
}

extern "C" void kernel_launch(void* const* d_in, const int* in_sizes, int n_in,
                              void* d_out, int out_size, void* d_ws, size_t ws_size,
                              hipStream_t stream) {
    (void)in_sizes; (void)n_in; (void)out_size; (void)ws_size;
    const float* x   = (const float*)d_in[0];
    const float* Wih = (const float*)d_in[1];
    const float* Whh = (const float*)d_in[2];
    const float* bih = (const float*)d_in[3];
    const float* bhh = (const float*)d_in[4];
    const float* Wfc = (const float*)d_in[5];
    const float* bfc = (const float*)d_in[6];
    float* out = (float*)d_out;

    char* ws = (char*)d_ws;
    _Float16* W16   = (_Float16*)(ws + OFF_W16);
    _Float16* Wih16 = (_Float16*)(ws + OFF_WIH);
    float*    biasf = (float*)(ws + OFF_BIAS);
    _Float16* x16   = (_Float16*)(ws + OFF_X16);
    _Float16* h0b   = (_Float16*)(ws + OFF_H0);
    _Float16* h1b   = (_Float16*)(ws + OFF_H1);
    unsigned* ctrb  = (unsigned*)(ws + OFF_CTR);

    hipLaunchKernelGGL(prep_w, dim3((2048 * 512) / 256), dim3(256), 0, stream,
                       Wih, Whh, bih, bhh, W16, Wih16, biasf, h0b, ctrb);
    hipLaunchKernelGGL(prep_x, dim3((512 * 256 * 64) / 256), dim3(256), 0, stream, x, x16);
    hipLaunchKernelGGL(lstm_k, dim3(128), dim3(256), 0, stream,
                       W16, Wih16, biasf, x16, h0b, h1b, ctrb);
    // T=512 even: last write went to buffer 0
    hipLaunchKernelGGL(fc_k, dim3(256), dim3(64), 0, stream, h0b, Wfc, bfc, out);
}